// Round 1
// baseline (108.954 us; speedup 1.0000x reference)
//
#include <hip/hip_runtime.h>
#include <stdint.h>

#define NROWS 8192
#define HALF_N 4096
#define DIM 512          /* elements per row; == bytes per row in fp8 */
#define INV_TEMP 2.0f
#define E2SCALE 2.8853900817779268f  /* INV_TEMP * log2(e) */
#define LN2 0.6931471805599453f
#define NTILES 2080
#define NXCD 8
#define TPX (NTILES / NXCD)  /* 260; NTILES % 8 == 0 so the swizzle is bijective */

typedef int i32x8 __attribute__((ext_vector_type(8)));
typedef float f32x16 __attribute__((ext_vector_type(16)));

// global -> LDS direct copy, 16B per lane; LDS dest is wave-uniform base + lane*16
__device__ __forceinline__ void gload_lds16(const unsigned char* g, unsigned char* l) {
  __builtin_amdgcn_global_load_lds(
      (const __attribute__((address_space(1))) unsigned int*)(uintptr_t)g,
      (__attribute__((address_space(3))) unsigned int*)(uint32_t)(uintptr_t)l,
      16, 0, 0);
}

// One wave per row: sumsq -> rsqrt -> fp8 e4m3 store (4 MB). Zeroes sumexp + ticket.
__global__ void __launch_bounds__(256) k_normalize(const float* __restrict__ zi,
                                                   const float* __restrict__ zj,
                                                   unsigned char* __restrict__ zn,
                                                   float* __restrict__ sumexp,
                                                   unsigned int* __restrict__ ticket) {
  int tid = threadIdx.x;
  int gid = blockIdx.x * 256 + tid;
  if (gid < NROWS) sumexp[gid] = 0.0f;
  if (gid == 0) *ticket = 0u;
  int wave = tid >> 6, lane = tid & 63;
  int row = blockIdx.x * 4 + wave;
  const float* src = (row < HALF_N) ? (zi + (size_t)row * DIM)
                                    : (zj + (size_t)(row - HALF_N) * DIM);
  const float4* s4 = (const float4*)src;
  float4 a = s4[lane];        // cols 4*lane .. +3
  float4 b = s4[lane + 64];   // cols 256+4*lane .. +3
  float ss = a.x * a.x + a.y * a.y + a.z * a.z + a.w * a.w +
             b.x * b.x + b.y * b.y + b.z * b.z + b.w * b.w;
#pragma unroll
  for (int off = 32; off > 0; off >>= 1) ss += __shfl_xor(ss, off, 64);
  float inv = 1.0f / fmaxf(sqrtf(ss), 1e-8f);
  int w0 = __builtin_amdgcn_cvt_pk_fp8_f32(a.x * inv, a.y * inv, 0, false);
  w0 = __builtin_amdgcn_cvt_pk_fp8_f32(a.z * inv, a.w * inv, w0, true);
  int w1 = __builtin_amdgcn_cvt_pk_fp8_f32(b.x * inv, b.y * inv, 0, false);
  w1 = __builtin_amdgcn_cvt_pk_fp8_f32(b.z * inv, b.w * inv, w1, true);
  unsigned char* dst = zn + (size_t)row * DIM;
  *((int*)(dst + lane * 4)) = w0;
  *((int*)(dst + 256 + lane * 4)) = w1;
}

// Upper-triangular 128x128 tiles (sim symmetric): off-diag tiles feed row- AND col-sums.
// MX-fp8 32x32x64 MFMA (scales = 2^0), 8 k-windows (BK=64 B) double-buffered in 32 KB LDS.
// Changes this round:
//  (1) epilogue folds exp/row-sums IN PLACE into acc[i][0] (rp[32] eliminated, -32 VGPR)
//      + __launch_bounds__(256,4) -> target 4 blocks/CU (was ~3, VGPR-capped).
//  (2) final LSE reduction fused via last-block ticket (agent-scope/sc1 for cross-XCD
//      visibility; relaxed RMW after __syncthreads so no per-block release-fence storm).
//  (3) XCD-bijective tile swizzle: tiles sharing a B-panel land on one XCD's L2.
__global__ void __launch_bounds__(256, 4) k_simsum(const unsigned char* __restrict__ zn,
                                                   float* __restrict__ sumexp,
                                                   float* __restrict__ posv,
                                                   unsigned int* __restrict__ ticket,
                                                   float* __restrict__ out) {
  __shared__ __align__(16) unsigned char As[2][128 * 64];  // 2 x 8 KB
  __shared__ __align__(16) unsigned char Bs[2][128 * 64];  // 2 x 8 KB
  __shared__ unsigned int lastFlag;
  __shared__ float fred[4];
  int tid = threadIdx.x;
  int wave = tid >> 6, lane = tid & 63;

  // XCD-aware bijective swizzle (2080 = 8*260): consecutive idx share tn (B-panel).
  int bswz = (blockIdx.x & (NXCD - 1)) * TPX + (blockIdx.x >> 3);
  // triangular decode, tn-major: idx = tn(tn+1)/2 + tm, tm <= tn
  int idx = bswz;
  int tn = (int)((sqrtf(8.0f * idx + 1.0f) - 1.0f) * 0.5f);
  while (tn * (tn + 1) / 2 > idx) tn--;
  while ((tn + 1) * (tn + 2) / 2 <= idx) tn++;
  int tm = idx - tn * (tn + 1) / 2;
  int rowBase = tm * 128, colBase = tn * 128;
  int wr = (wave >> 1) * 64, wc = (wave & 1) * 64;  // wave's 64x64 quadrant
  int h = lane >> 5, c32 = lane & 31;               // k-half and matrix row/col in 32-block

  // staging: wave stages 32 rows of A and B per window; 16B/lane; 4 lanes per 64-B row.
  // Physical granule p of row r holds source k-chunk p ^ ((r>>1)&3).
  int rA = wave * 32 + (lane >> 2);
  int chunk = (lane & 3) ^ ((rA >> 1) & 3);
  const unsigned char* gA = zn + (size_t)(rowBase + rA) * DIM + chunk * 16;
  const unsigned char* gB = zn + (size_t)(colBase + rA) * DIM + chunk * 16;
  unsigned char* lA[2] = {&As[0][wave * 2048], &As[1][wave * 2048]};
  unsigned char* lB[2] = {&Bs[0][wave * 2048], &Bs[1][wave * 2048]};

#define STAGE(b)                                  \
  do {                                            \
    gload_lds16(gA, lA[b]);                       \
    gload_lds16(gA + 16 * DIM, lA[b] + 1024);     \
    gload_lds16(gB, lB[b]);                       \
    gload_lds16(gB + 16 * DIM, lB[b] + 1024);     \
    gA += 64; gB += 64;                           \
  } while (0)

  f32x16 acc[2][2];
#pragma unroll
  for (int i = 0; i < 2; i++)
#pragma unroll
    for (int j = 0; j < 2; j++)
#pragma unroll
      for (int r = 0; r < 16; r++) acc[i][j][r] = 0.f;

  // Fragment read indices (int4 = one 16-B granule; row r at granule r*4).
  // Lane (c32,h) needs row-bytes k = h*32 + 0..31 -> granules 2h, 2h+1, XOR-swizzled.
  int sg = (c32 >> 1) & 3;           // == ((wr|wc + i*32 + c32)>>1)&3 (wr,wc,32 mult of 32)
  int p0 = (2 * h) ^ sg, p1 = p0 ^ 1;
  int aIdx[2] = {(wr + c32) * 4, (wr + 32 + c32) * 4};
  int bIdx[2] = {(wc + c32) * 4, (wc + 32 + c32) * 4};

#define COMPUTE(b)                                                                   \
  do {                                                                               \
    const int4* Av = (const int4*)As[b];                                             \
    const int4* Bv = (const int4*)Bs[b];                                             \
    i32x8 af[2], bfr[2];                                                             \
    _Pragma("unroll") for (int i = 0; i < 2; i++) {                                  \
      int4 lo = Av[aIdx[i] + p0], hi = Av[aIdx[i] + p1];                             \
      af[i] = (i32x8){lo.x, lo.y, lo.z, lo.w, hi.x, hi.y, hi.z, hi.w};               \
    }                                                                                \
    _Pragma("unroll") for (int j = 0; j < 2; j++) {                                  \
      int4 lo = Bv[bIdx[j] + p0], hi = Bv[bIdx[j] + p1];                             \
      bfr[j] = (i32x8){lo.x, lo.y, lo.z, lo.w, hi.x, hi.y, hi.z, hi.w};              \
    }                                                                                \
    _Pragma("unroll") for (int i = 0; i < 2; i++)                                    \
      _Pragma("unroll") for (int j = 0; j < 2; j++)                                  \
        acc[i][j] = __builtin_amdgcn_mfma_scale_f32_32x32x64_f8f6f4(                 \
            af[i], bfr[j], acc[i][j], 0, 0, /*fp8,fp8*/                              \
            0, 0x7F, 0, 0x7F);            /* scales = 2^0 */                         \
  } while (0)

  STAGE(0);  // prologue: k-window 0
#pragma unroll
  for (int s = 0; s < 8; s += 2) {
    __syncthreads();           // drains window-s loads (in flight one full phase)
    if (s + 1 < 8) STAGE(1);   // issue window s+1 before computing s
    COMPUTE(0);
    __syncthreads();
    if (s + 2 < 8) STAGE(0);
    COMPUTE(1);
  }

  // ---- Epilogue. 32x32 C/D layout: col = lane&31, row = (reg&3)+8*(reg>>2)+4*h. ----
  bool isDiag = (tm == tn);
  bool hasPos = (tn == tm + 32);
  bool diagLane = (wr == wc) && (h == ((c32 >> 2) & 1));  // lane holding row==col elems
  int rsel = (c32 & 3) | ((c32 >> 3) << 2);               // reg with rowIn32 == c32

  if (isDiag && diagLane) {
    acc[0][0][rsel] = -1e30f;  // exp2 -> 0 (mask diagonal)
    acc[1][1][rsel] = -1e30f;
  }
  if (hasPos && diagLane) {
#pragma unroll
    for (int i = 0; i < 2; i++) {
      float sv = acc[i][i][rsel] * INV_TEMP;
      int gr = rowBase + wr + i * 32 + c32;
      // unique (row,col) across grid; agent-scope (sc1) store -> lands at LLC so the
      // fused final phase (possibly another XCD) sees it without a kernel boundary.
      __hip_atomic_store(&posv[gr], sv, __ATOMIC_RELAXED, __HIP_MEMORY_SCOPE_AGENT);
      __hip_atomic_store(&posv[gr + HALF_N], sv, __ATOMIC_RELAXED, __HIP_MEMORY_SCOPE_AGENT);
    }
  }

  // exp2 + row-partials IN PLACE: acc[i][0][r] <- e0+e1 (rp[32] eliminated -> -32 VGPR).
  float cp[2] = {0.f, 0.f};
#pragma unroll
  for (int i = 0; i < 2; i++)
#pragma unroll
    for (int r = 0; r < 16; r++) {
      float e0 = __builtin_amdgcn_exp2f(acc[i][0][r] * E2SCALE);
      float e1 = __builtin_amdgcn_exp2f(acc[i][1][r] * E2SCALE);
      cp[0] += e0;
      cp[1] += e1;
      acc[i][0][r] = e0 + e1;
    }

#define RP(t) acc[(t) >> 4][0][(t) & 15]
  // Fold-reduce the 32 row-partials across the 32-lane half; lane ends with v = c32.
#pragma unroll
  for (int t = 0; t < 16; t++) {
    float mine = (lane & 16) ? RP(t + 16) : RP(t);
    float oth = __shfl_xor((lane & 16) ? RP(t) : RP(t + 16), 16, 64);
    RP(t) = mine + oth;
  }
#pragma unroll
  for (int t = 0; t < 8; t++) {
    float mine = (lane & 8) ? RP(t + 8) : RP(t);
    float oth = __shfl_xor((lane & 8) ? RP(t) : RP(t + 8), 8, 64);
    RP(t) = mine + oth;
  }
#pragma unroll
  for (int t = 0; t < 4; t++) {
    float mine = (lane & 4) ? RP(t + 4) : RP(t);
    float oth = __shfl_xor((lane & 4) ? RP(t) : RP(t + 4), 4, 64);
    RP(t) = mine + oth;
  }
#pragma unroll
  for (int t = 0; t < 2; t++) {
    float mine = (lane & 2) ? RP(t + 2) : RP(t);
    float oth = __shfl_xor((lane & 2) ? RP(t) : RP(t + 2), 2, 64);
    RP(t) = mine + oth;
  }
  {
    float mine = (lane & 1) ? RP(1) : RP(0);
    float oth = __shfl_xor((lane & 1) ? RP(0) : RP(1), 1, 64);
    RP(0) = mine + oth;
  }
  // lane's row: i = c32>>4, reg = c32&15 -> rowIn32 = (c32&3) + 8*((c32>>2)&3) + 4*h
  int myrow = rowBase + wr + 32 * (c32 >> 4) + (c32 & 3) + 8 * ((c32 >> 2) & 3) + 4 * h;
  atomicAdd(&sumexp[myrow], RP(0));
#undef RP

  if (!isDiag) {
    // col sums: sum the two k-halves' contributions, then lane h picks col-block j=h
    cp[0] += __shfl_xor(cp[0], 32, 64);
    cp[1] += __shfl_xor(cp[1], 32, 64);
    float cv = h ? cp[1] : cp[0];
    atomicAdd(&sumexp[colBase + wc + h * 32 + c32], cv);
  }

  // ---- Fused final phase (replaces k_final): last block reduces. ----
  // __syncthreads drains every wave's vmcnt -> this block's atomics / sc1 stores have
  // retired at the LLC (coherence point) before we signal. Relaxed RMW: no release
  // fence, so no per-block L2-writeback storm (R5 lesson).
  __syncthreads();
  if (tid == 0) {
    unsigned int old = __hip_atomic_fetch_add(ticket, 1u, __ATOMIC_RELAXED,
                                              __HIP_MEMORY_SCOPE_AGENT);
    lastFlag = (old == (unsigned int)(NTILES - 1)) ? 1u : 0u;
  }
  __syncthreads();
  if (lastFlag) {  // block-uniform branch
    float p = 0.f;
#pragma unroll
    for (int it = 0; it < 8; it++) {
      int j = it * 1024 + tid;
      // agent-scope loads (sc1) bypass this XCD's L2 -> read the LLC, where all
      // blocks' atomicAdds and posv stores live.
      float s0 = __hip_atomic_load(&sumexp[j], __ATOMIC_RELAXED, __HIP_MEMORY_SCOPE_AGENT);
      float s1 = __hip_atomic_load(&sumexp[j + 256], __ATOMIC_RELAXED, __HIP_MEMORY_SCOPE_AGENT);
      float s2 = __hip_atomic_load(&sumexp[j + 512], __ATOMIC_RELAXED, __HIP_MEMORY_SCOPE_AGENT);
      float s3 = __hip_atomic_load(&sumexp[j + 768], __ATOMIC_RELAXED, __HIP_MEMORY_SCOPE_AGENT);
      float q0 = __hip_atomic_load(&posv[j], __ATOMIC_RELAXED, __HIP_MEMORY_SCOPE_AGENT);
      float q1 = __hip_atomic_load(&posv[j + 256], __ATOMIC_RELAXED, __HIP_MEMORY_SCOPE_AGENT);
      float q2 = __hip_atomic_load(&posv[j + 512], __ATOMIC_RELAXED, __HIP_MEMORY_SCOPE_AGENT);
      float q3 = __hip_atomic_load(&posv[j + 768], __ATOMIC_RELAXED, __HIP_MEMORY_SCOPE_AGENT);
      p += (__builtin_amdgcn_logf(s0) + __builtin_amdgcn_logf(s1) +
            __builtin_amdgcn_logf(s2) + __builtin_amdgcn_logf(s3)) * LN2 -
           (q0 + q1 + q2 + q3);
    }
#pragma unroll
    for (int off = 32; off > 0; off >>= 1) p += __shfl_xor(p, off, 64);
    if (lane == 0) fred[wave] = p;
    __syncthreads();
    if (tid == 0)
      out[0] = (fred[0] + fred[1] + fred[2] + fred[3]) / (float)NROWS;
  }
#undef STAGE
#undef COMPUTE
}

extern "C" void kernel_launch(void* const* d_in, const int* in_sizes, int n_in,
                              void* d_out, int out_size, void* d_ws, size_t ws_size,
                              hipStream_t stream) {
  const float* zi = (const float*)d_in[0];
  const float* zj = (const float*)d_in[1];
  unsigned char* zn = (unsigned char*)d_ws;                           // 4 MB fp8
  float* sumexp = (float*)((char*)d_ws + (size_t)NROWS * DIM);        // 32 KB
  float* posv = sumexp + NROWS;                                       // 32 KB
  unsigned int* ticket = (unsigned int*)(posv + NROWS);               // 4 B
  float* out = (float*)d_out;

  hipLaunchKernelGGL(k_normalize, dim3(2048), dim3(256), 0, stream, zi, zj, zn, sumexp, ticket);
  hipLaunchKernelGGL(k_simsum, dim3(NTILES), dim3(256), 0, stream, zn, sumexp, posv, ticket, out);
}

// Round 2
// 91.060 us; speedup vs baseline: 1.1965x; 1.1965x over previous
//
#include <hip/hip_runtime.h>
#include <stdint.h>

#define NROWS 8192
#define HALF_N 4096
#define DIM 512          /* elements per row; == bytes per row in fp8 */
#define INV_TEMP 2.0f
#define E2SCALE 2.8853900817779268f  /* INV_TEMP * log2(e) */
#define LN2 0.6931471805599453f
#define NTILES 2080
#define NXCD 8
#define TPX (NTILES / NXCD)  /* 260; NTILES % 8 == 0 so the swizzle is bijective */

typedef int i32x8 __attribute__((ext_vector_type(8)));
typedef float f32x16 __attribute__((ext_vector_type(16)));

// global -> LDS direct copy, 16B per lane; LDS dest is wave-uniform base + lane*16
__device__ __forceinline__ void gload_lds16(const unsigned char* g, unsigned char* l) {
  __builtin_amdgcn_global_load_lds(
      (const __attribute__((address_space(1))) unsigned int*)(uintptr_t)g,
      (__attribute__((address_space(3))) unsigned int*)(uint32_t)(uintptr_t)l,
      16, 0, 0);
}

// One wave per row: sumsq -> rsqrt -> fp8 e4m3 store (4 MB). Zeroes sumexp.
__global__ void __launch_bounds__(256) k_normalize(const float* __restrict__ zi,
                                                   const float* __restrict__ zj,
                                                   unsigned char* __restrict__ zn,
                                                   float* __restrict__ sumexp) {
  int tid = threadIdx.x;
  int gid = blockIdx.x * 256 + tid;
  if (gid < NROWS) sumexp[gid] = 0.0f;
  int wave = tid >> 6, lane = tid & 63;
  int row = blockIdx.x * 4 + wave;
  const float* src = (row < HALF_N) ? (zi + (size_t)row * DIM)
                                    : (zj + (size_t)(row - HALF_N) * DIM);
  const float4* s4 = (const float4*)src;
  float4 a = s4[lane];        // cols 4*lane .. +3
  float4 b = s4[lane + 64];   // cols 256+4*lane .. +3
  float ss = a.x * a.x + a.y * a.y + a.z * a.z + a.w * a.w +
             b.x * b.x + b.y * b.y + b.z * b.z + b.w * b.w;
#pragma unroll
  for (int off = 32; off > 0; off >>= 1) ss += __shfl_xor(ss, off, 64);
  float inv = 1.0f / fmaxf(sqrtf(ss), 1e-8f);
  int w0 = __builtin_amdgcn_cvt_pk_fp8_f32(a.x * inv, a.y * inv, 0, false);
  w0 = __builtin_amdgcn_cvt_pk_fp8_f32(a.z * inv, a.w * inv, w0, true);
  int w1 = __builtin_amdgcn_cvt_pk_fp8_f32(b.x * inv, b.y * inv, 0, false);
  w1 = __builtin_amdgcn_cvt_pk_fp8_f32(b.z * inv, b.w * inv, w1, true);
  unsigned char* dst = zn + (size_t)row * DIM;
  *((int*)(dst + lane * 4)) = w0;
  *((int*)(dst + 256 + lane * 4)) = w1;
}

// Upper-triangular 128x128 tiles (sim symmetric): off-diag tiles feed row- AND col-sums.
// MX-fp8 32x32x64 MFMA (scales = 2^0).
// R2 change: K-loop restructured from {2-buffer, syncthreads (vmcnt(0) drain) per window}
// to {3-buffer, depth-2 prefetch, counted vmcnt(4), raw s_barrier} — T3+T4 from the
// catalog. Each window's global_load_lds now has ~2 compute phases in flight before its
// counted wait, and younger loads cross the barrier un-drained. T5 setprio around MFMA.
// Fused last-block tail REVERTED (R1 lesson: 4-wave agent-scope tail slower than k_final).
__global__ void __launch_bounds__(256, 3) k_simsum(const unsigned char* __restrict__ zn,
                                                   float* __restrict__ sumexp,
                                                   float* __restrict__ posv) {
  __shared__ __align__(16) unsigned char As[3][128 * 64];  // 3 x 8 KB
  __shared__ __align__(16) unsigned char Bs[3][128 * 64];  // 3 x 8 KB
  int tid = threadIdx.x;
  int wave = tid >> 6, lane = tid & 63;

  // XCD-aware bijective swizzle (2080 = 8*260): consecutive idx share tn (B-panel).
  int bswz = (blockIdx.x & (NXCD - 1)) * TPX + (blockIdx.x >> 3);
  // triangular decode, tn-major: idx = tn(tn+1)/2 + tm, tm <= tn
  int idx = bswz;
  int tn = (int)((sqrtf(8.0f * idx + 1.0f) - 1.0f) * 0.5f);
  while (tn * (tn + 1) / 2 > idx) tn--;
  while ((tn + 1) * (tn + 2) / 2 <= idx) tn++;
  int tm = idx - tn * (tn + 1) / 2;
  int rowBase = tm * 128, colBase = tn * 128;
  int wr = (wave >> 1) * 64, wc = (wave & 1) * 64;  // wave's 64x64 quadrant
  int h = lane >> 5, c32 = lane & 31;               // k-half and matrix row/col in 32-block

  // staging: wave stages 32 rows of A and B per window; 16B/lane; 4 lanes per 64-B row.
  // Physical granule p of row r holds source k-chunk p ^ ((r>>1)&3).
  int rA = wave * 32 + (lane >> 2);
  int chunk = (lane & 3) ^ ((rA >> 1) & 3);
  const unsigned char* gA = zn + (size_t)(rowBase + rA) * DIM + chunk * 16;
  const unsigned char* gB = zn + (size_t)(colBase + rA) * DIM + chunk * 16;

#define STAGE(b)                                          \
  do {                                                    \
    gload_lds16(gA, &As[b][wave * 2048]);                 \
    gload_lds16(gA + 16 * DIM, &As[b][wave * 2048 + 1024]); \
    gload_lds16(gB, &Bs[b][wave * 2048]);                 \
    gload_lds16(gB + 16 * DIM, &Bs[b][wave * 2048 + 1024]); \
    gA += 64; gB += 64;                                   \
  } while (0)

  f32x16 acc[2][2];
#pragma unroll
  for (int i = 0; i < 2; i++)
#pragma unroll
    for (int j = 0; j < 2; j++)
#pragma unroll
      for (int r = 0; r < 16; r++) acc[i][j][r] = 0.f;

  // Fragment read indices (int4 = one 16-B granule; row r at granule r*4).
  // Lane (c32,h) needs row-bytes k = h*32 + 0..31 -> granules 2h, 2h+1, XOR-swizzled.
  int sg = (c32 >> 1) & 3;           // == ((wr|wc + i*32 + c32)>>1)&3 (wr,wc,32 mult of 32)
  int p0 = (2 * h) ^ sg, p1 = p0 ^ 1;
  int aIdx[2] = {(wr + c32) * 4, (wr + 32 + c32) * 4};
  int bIdx[2] = {(wc + c32) * 4, (wc + 32 + c32) * 4};

#define COMPUTE(b)                                                                   \
  do {                                                                               \
    const int4* Av = (const int4*)As[b];                                             \
    const int4* Bv = (const int4*)Bs[b];                                             \
    i32x8 af[2], bfr[2];                                                             \
    _Pragma("unroll") for (int i = 0; i < 2; i++) {                                  \
      int4 lo = Av[aIdx[i] + p0], hi = Av[aIdx[i] + p1];                             \
      af[i] = (i32x8){lo.x, lo.y, lo.z, lo.w, hi.x, hi.y, hi.z, hi.w};               \
    }                                                                                \
    _Pragma("unroll") for (int j = 0; j < 2; j++) {                                  \
      int4 lo = Bv[bIdx[j] + p0], hi = Bv[bIdx[j] + p1];                             \
      bfr[j] = (i32x8){lo.x, lo.y, lo.z, lo.w, hi.x, hi.y, hi.z, hi.w};              \
    }                                                                                \
    __builtin_amdgcn_s_setprio(1);                                                   \
    _Pragma("unroll") for (int i = 0; i < 2; i++)                                    \
      _Pragma("unroll") for (int j = 0; j < 2; j++)                                  \
        acc[i][j] = __builtin_amdgcn_mfma_scale_f32_32x32x64_f8f6f4(                 \
            af[i], bfr[j], acc[i][j], 0, 0, /*fp8,fp8*/                              \
            0, 0x7F, 0, 0x7F);            /* scales = 2^0 */                         \
    __builtin_amdgcn_s_setprio(0);                                                   \
  } while (0)

  // ---- Deep-pipelined K loop: 3 buffers, depth-2 prefetch, counted vmcnt. ----
  // Window s lives in buffer s%3. STAGE(w_{s+2}) is issued at iter s (post-barrier),
  // overwriting w_{s-1}, whose readers drained lgkmcnt before this iter's barrier.
  // vmcnt(4): at iter-s entry the outstanding loads are w_s(4)+w_{s+1}(4); waiting to 4
  // completes w_s (issued 2 phases earlier) while w_{s+1} stays in flight. Last iter: 0.
#define ASM_VMCNT(n) asm volatile("s_waitcnt vmcnt(" #n ")" ::: "memory")
#define WINDOW(s, vm)                                        \
  do {                                                       \
    ASM_VMCNT(vm);                                           \
    asm volatile("s_waitcnt lgkmcnt(0)" ::: "memory");       \
    __builtin_amdgcn_sched_barrier(0);                       \
    __builtin_amdgcn_s_barrier();                            \
    __builtin_amdgcn_sched_barrier(0);                       \
    if ((s) + 2 < 8) STAGE(((s) + 2) % 3);                   \
    COMPUTE((s) % 3);                                        \
  } while (0)

  STAGE(0);  // w0
  STAGE(1);  // w1
  WINDOW(0, 4);
  WINDOW(1, 4);
  WINDOW(2, 4);
  WINDOW(3, 4);
  WINDOW(4, 4);
  WINDOW(5, 4);
  WINDOW(6, 4);
  WINDOW(7, 0);

  // ---- Epilogue. 32x32 C/D layout: col = lane&31, row = (reg&3)+8*(reg>>2)+4*h. ----
  bool isDiag = (tm == tn);
  bool hasPos = (tn == tm + 32);
  bool diagLane = (wr == wc) && (h == ((c32 >> 2) & 1));  // lane holding row==col elems
  int rsel = (c32 & 3) | ((c32 >> 3) << 2);               // reg with rowIn32 == c32

  if (isDiag && diagLane) {
    acc[0][0][rsel] = -1e30f;  // exp2 -> 0 (mask diagonal)
    acc[1][1][rsel] = -1e30f;
  }
  if (hasPos && diagLane) {
#pragma unroll
    for (int i = 0; i < 2; i++) {
      float sv = acc[i][i][rsel] * INV_TEMP;
      int gr = rowBase + wr + i * 32 + c32;
      posv[gr] = sv;            // unique (row,col) across grid -> race-free plain store
      posv[gr + HALF_N] = sv;   // sim symmetric
    }
  }

  // exp2 + row-partials IN PLACE: acc[i][0][r] <- e0+e1 (saves the rp[32] array).
  float cp[2] = {0.f, 0.f};
#pragma unroll
  for (int i = 0; i < 2; i++)
#pragma unroll
    for (int r = 0; r < 16; r++) {
      float e0 = __builtin_amdgcn_exp2f(acc[i][0][r] * E2SCALE);
      float e1 = __builtin_amdgcn_exp2f(acc[i][1][r] * E2SCALE);
      cp[0] += e0;
      cp[1] += e1;
      acc[i][0][r] = e0 + e1;
    }

#define RP(t) acc[(t) >> 4][0][(t) & 15]
  // Fold-reduce the 32 row-partials across the 32-lane half; lane ends with v = c32.
#pragma unroll
  for (int t = 0; t < 16; t++) {
    float mine = (lane & 16) ? RP(t + 16) : RP(t);
    float oth = __shfl_xor((lane & 16) ? RP(t) : RP(t + 16), 16, 64);
    RP(t) = mine + oth;
  }
#pragma unroll
  for (int t = 0; t < 8; t++) {
    float mine = (lane & 8) ? RP(t + 8) : RP(t);
    float oth = __shfl_xor((lane & 8) ? RP(t) : RP(t + 8), 8, 64);
    RP(t) = mine + oth;
  }
#pragma unroll
  for (int t = 0; t < 4; t++) {
    float mine = (lane & 4) ? RP(t + 4) : RP(t);
    float oth = __shfl_xor((lane & 4) ? RP(t) : RP(t + 4), 4, 64);
    RP(t) = mine + oth;
  }
#pragma unroll
  for (int t = 0; t < 2; t++) {
    float mine = (lane & 2) ? RP(t + 2) : RP(t);
    float oth = __shfl_xor((lane & 2) ? RP(t) : RP(t + 2), 2, 64);
    RP(t) = mine + oth;
  }
  {
    float mine = (lane & 1) ? RP(1) : RP(0);
    float oth = __shfl_xor((lane & 1) ? RP(0) : RP(1), 1, 64);
    RP(0) = mine + oth;
  }
  // lane's row: i = c32>>4, reg = c32&15 -> rowIn32 = (c32&3) + 8*((c32>>2)&3) + 4*h
  int myrow = rowBase + wr + 32 * (c32 >> 4) + (c32 & 3) + 8 * ((c32 >> 2) & 3) + 4 * h;
  atomicAdd(&sumexp[myrow], RP(0));
#undef RP

  if (!isDiag) {
    // col sums: sum the two k-halves' contributions, then lane h picks col-block j=h
    cp[0] += __shfl_xor(cp[0], 32, 64);
    cp[1] += __shfl_xor(cp[1], 32, 64);
    float cv = h ? cp[1] : cp[0];
    atomicAdd(&sumexp[colBase + wc + h * 32 + c32], cv);
  }
#undef STAGE
#undef COMPUTE
#undef WINDOW
#undef ASM_VMCNT
}

__global__ void __launch_bounds__(1024) k_final(const float* __restrict__ sumexp,
                                                const float* __restrict__ posv,
                                                float* __restrict__ out) {
  __shared__ float red[16];
  int tid = threadIdx.x;
  const float4* se4 = (const float4*)sumexp;
  const float4* pv4 = (const float4*)posv;
  float p = 0.f;
#pragma unroll
  for (int c = 0; c < 2; c++) {
    float4 se = se4[tid * 2 + c];
    float4 pv = pv4[tid * 2 + c];
    p += (__builtin_amdgcn_logf(se.x) + __builtin_amdgcn_logf(se.y) +
          __builtin_amdgcn_logf(se.z) + __builtin_amdgcn_logf(se.w)) * LN2 -
         (pv.x + pv.y + pv.z + pv.w);
  }
#pragma unroll
  for (int off = 32; off > 0; off >>= 1) p += __shfl_xor(p, off, 64);
  int wv = tid >> 6, ln = tid & 63;
  if (ln == 0) red[wv] = p;
  __syncthreads();
  if (tid == 0) {
    float t = 0.f;
    for (int w = 0; w < 16; w++) t += red[w];
    out[0] = t / (float)NROWS;
  }
}

extern "C" void kernel_launch(void* const* d_in, const int* in_sizes, int n_in,
                              void* d_out, int out_size, void* d_ws, size_t ws_size,
                              hipStream_t stream) {
  const float* zi = (const float*)d_in[0];
  const float* zj = (const float*)d_in[1];
  unsigned char* zn = (unsigned char*)d_ws;                           // 4 MB fp8
  float* sumexp = (float*)((char*)d_ws + (size_t)NROWS * DIM);        // 32 KB
  float* posv = sumexp + NROWS;                                       // 32 KB
  float* out = (float*)d_out;

  hipLaunchKernelGGL(k_normalize, dim3(2048), dim3(256), 0, stream, zi, zj, zn, sumexp);
  hipLaunchKernelGGL(k_simsum, dim3(NTILES), dim3(256), 0, stream, zn, sumexp, posv);
  hipLaunchKernelGGL(k_final, dim3(1), dim3(1024), 0, stream, sumexp, posv, out);
}